// Round 1
// baseline (49.338 us; speedup 1.0000x reference)
//
#include <hip/hip_runtime.h>
#include <math.h>

// Problem constants (fixed by setup_inputs):
//   outputs: [8, 512, 12]            fp32
//   targets: [8, 512, 1, 2, 128]     fp32
//   W_dec:   [12, 256]               fp32
//   b_dec:   [256]                   fp32
//   out:     scalar fp32
#define NCOMP 12
#define NS 128
#define NBS 4096   // 8 * 512

__global__ __launch_bounds__(256)
void p2cp_block_kernel(const float* __restrict__ outputs,
                       const float* __restrict__ targets,
                       const float* __restrict__ W_dec,
                       const float* __restrict__ b_dec,
                       float* __restrict__ partial) {
    const int bsq = blockIdx.x;      // flattened (b, s)
    const int t   = threadIdx.x;     // 0..255

    __shared__ float ux[NS], uy[NS], vx[NS], vy[NS];
    __shared__ float o[NCOMP];
    __shared__ float red[4];

    if (t < NCOMP) o[t] = outputs[bsq * NCOMP + t];
    __syncthreads();

    // Decode: shapes[t] = b_dec[t] + sum_k o[k] * W_dec[k*256 + t]
    float acc = b_dec[t];
    #pragma unroll
    for (int k = 0; k < NCOMP; ++k)
        acc = fmaf(o[k], W_dec[k * 256 + t], acc);

    // u point i: x = shapes[i], y = shapes[128 + i]
    if (t < NS) ux[t] = acc; else uy[t - NS] = acc;

    // targets layout per (b,s): [2][128]; v point j: x = tb[j], y = tb[128+j]
    const float* tb = targets + (size_t)bsq * (2 * NS);
    if (t < NS) vx[t] = tb[t]; else vy[t - NS] = tb[t];
    __syncthreads();

    // Threads 0..127: row-min over v for u-point t.
    // Threads 128..255: col-min over u for v-point t-128.
    // min over sqrt(d2 + EPS) == sqrt(min(d2) + EPS)  (sqrt monotone) -> one sqrt.
    float m2 = 3.0e38f;
    if (t < NS) {
        const float x = ux[t], y = uy[t];
        #pragma unroll 4
        for (int j = 0; j < NS; ++j) {
            float dx = x - vx[j];
            float dy = y - vy[j];
            float d2 = fmaf(dx, dx, dy * dy);
            m2 = fminf(m2, d2);
        }
    } else {
        const int j = t - NS;
        const float x = vx[j], y = vy[j];
        #pragma unroll 4
        for (int i = 0; i < NS; ++i) {
            float dx = x - ux[i];
            float dy = y - uy[i];
            float d2 = fmaf(dx, dx, dy * dy);
            m2 = fminf(m2, d2);
        }
    }
    float m = sqrtf(m2 + 1e-12f);

    // Block sum of m across 256 threads (wave64 shuffle + LDS).
    #pragma unroll
    for (int off = 32; off > 0; off >>= 1)
        m += __shfl_down(m, off);
    const int lane = t & 63;
    const int wid  = t >> 6;
    if (lane == 0) red[wid] = m;
    __syncthreads();
    if (t == 0) {
        // per-(b,s) p2cp = (sum_rowmins + sum_colmins) / 256 = blocksum / 256
        partial[bsq] = red[0] + red[1] + red[2] + red[3];
    }
}

__global__ __launch_bounds__(256)
void final_reduce_kernel(const float* __restrict__ partial,
                         float* __restrict__ out) {
    const int t = threadIdx.x;
    float s = 0.0f;
    for (int i = t; i < NBS; i += 256) s += partial[i];
    #pragma unroll
    for (int off = 32; off > 0; off >>= 1)
        s += __shfl_down(s, off);
    __shared__ float red[4];
    const int lane = t & 63;
    const int wid  = t >> 6;
    if (lane == 0) red[wid] = s;
    __syncthreads();
    if (t == 0) {
        float total = red[0] + red[1] + red[2] + red[3];
        // divide by 256 (per-block pair count) and by 4096 (mean over b,s,n_art)
        out[0] = total * (1.0f / (256.0f * (float)NBS));
    }
}

extern "C" void kernel_launch(void* const* d_in, const int* in_sizes, int n_in,
                              void* d_out, int out_size, void* d_ws, size_t ws_size,
                              hipStream_t stream) {
    const float* outputs = (const float*)d_in[0];
    const float* targets = (const float*)d_in[1];
    const float* W_dec   = (const float*)d_in[2];
    const float* b_dec   = (const float*)d_in[3];
    float* out = (float*)d_out;
    float* ws  = (float*)d_ws;   // needs 4096 floats = 16 KB

    p2cp_block_kernel<<<NBS, 256, 0, stream>>>(outputs, targets, W_dec, b_dec, ws);
    final_reduce_kernel<<<1, 256, 0, stream>>>(ws, out);
}

// Round 2
// 42.237 us; speedup vs baseline: 1.1681x; 1.1681x over previous
//
#include <hip/hip_runtime.h>
#include <math.h>
#include <float.h>

// Problem constants (fixed by setup_inputs):
//   outputs: [8, 512, 12]            fp32
//   targets: [8, 512, 1, 2, 128]     fp32
//   W_dec:   [12, 256]               fp32
//   b_dec:   [256]                   fp32
//   out:     scalar fp32
#define NCOMP 12
#define NS 128
#define NBS 4096   // 8 * 512

__global__ __launch_bounds__(256)
void p2cp_block_kernel(const float* __restrict__ outputs,
                       const float* __restrict__ targets,
                       const float* __restrict__ W_dec,
                       const float* __restrict__ b_dec,
                       float* __restrict__ partial) {
    const int bsq = blockIdx.x;      // flattened (b, s)
    const int t   = threadIdx.x;     // 0..255

    __shared__ float4 pu[NS];        // {x, y, x^2+y^2, 0} for predicted points
    __shared__ float4 pv[NS];        // same for target points
    __shared__ float  tmp[2 * NS];   // staging: decoded shapes
    __shared__ float  o[NCOMP];
    __shared__ float  red[4];

    if (t < NCOMP) o[t] = outputs[bsq * NCOMP + t];

    // Stage target row (coalesced): per (b,s) layout [2][128]
    const float* tb = targets + (size_t)bsq * (2 * NS);
    const float tval = tb[t];
    __syncthreads();

    // Decode: shapes[t] = b_dec[t] + sum_k o[k] * W_dec[k*256 + t]
    float acc = b_dec[t];
    #pragma unroll
    for (int k = 0; k < NCOMP; ++k)
        acc = fmaf(o[k], W_dec[k * 256 + t], acc);
    tmp[t] = acc;

    // pack targets: thread t<128 owns v-point t (x = tb[t], y = tb[128+t])
    if (t < NS) {
        const float vy = tb[NS + t];           // second global read, coalesced
        pv[t] = make_float4(tval, vy, fmaf(tval, tval, vy * vy), 0.0f);
    }
    __syncthreads();

    // pack decoded u points: thread t>=128 owns u-point t-128
    if (t >= NS) {
        const int i = t - NS;
        const float x = tmp[i], y = tmp[NS + i];
        pu[i] = make_float4(x, y, fmaf(x, x, y * y), 0.0f);
    }
    __syncthreads();

    // Threads 0..127: min over v for u-point t (read pv).
    // Threads 128..255: min over u for v-point t-128 (read pu).
    // Gram form: d2(p,q) = |p|^2 + |q|^2 - 2 p.q
    //   min_q d2 = |p|^2 + min_q ( |q|^2 - 2x*qx - 2y*qy )
    const int i = t & (NS - 1);
    const float4 own = (t < NS) ? pu[i] : pv[i];
    const float4* __restrict__ opp = (t < NS) ? pv : pu;

    const float a = -2.0f * own.x;
    const float b = -2.0f * own.y;
    float mA = FLT_MAX, mB = FLT_MAX, mC = FLT_MAX, mD = FLT_MAX;
    #pragma unroll 4
    for (int j = 0; j < NS; j += 4) {
        const float4 q0 = opp[j + 0];
        const float4 q1 = opp[j + 1];
        const float4 q2 = opp[j + 2];
        const float4 q3 = opp[j + 3];
        mA = fminf(mA, fmaf(a, q0.x, fmaf(b, q0.y, q0.z)));
        mB = fminf(mB, fmaf(a, q1.x, fmaf(b, q1.y, q1.z)));
        mC = fminf(mC, fmaf(a, q2.x, fmaf(b, q2.y, q2.z)));
        mD = fminf(mD, fmaf(a, q3.x, fmaf(b, q3.y, q3.z)));
    }
    const float mm = fminf(fminf(mA, mB), fminf(mC, mD));
    const float d2 = fmaxf(mm + own.z, 0.0f);     // matches jnp.maximum(d2, 0)
    float m = sqrtf(d2 + 1e-12f);                 // sqrt(min(d2)+EPS) == min(sqrt(d2+EPS))

    // Block sum of m across 256 threads (wave64 shuffle + LDS).
    #pragma unroll
    for (int off = 32; off > 0; off >>= 1)
        m += __shfl_down(m, off);
    const int lane = t & 63;
    const int wid  = t >> 6;
    if (lane == 0) red[wid] = m;
    __syncthreads();
    if (t == 0) {
        // per-(b,s) p2cp contribution: (sum_rowmins + sum_colmins)
        partial[bsq] = red[0] + red[1] + red[2] + red[3];
    }
}

__global__ __launch_bounds__(256)
void final_reduce_kernel(const float* __restrict__ partial,
                         float* __restrict__ out) {
    const int t = threadIdx.x;
    float s = 0.0f;
    for (int i = t; i < NBS; i += 256) s += partial[i];
    #pragma unroll
    for (int off = 32; off > 0; off >>= 1)
        s += __shfl_down(s, off);
    __shared__ float red[4];
    const int lane = t & 63;
    const int wid  = t >> 6;
    if (lane == 0) red[wid] = s;
    __syncthreads();
    if (t == 0) {
        float total = red[0] + red[1] + red[2] + red[3];
        // 0.5*(u2v.mean + v2u.mean) per (b,s) = blocksum/256; then mean over 4096
        out[0] = total * (1.0f / (256.0f * (float)NBS));
    }
}

extern "C" void kernel_launch(void* const* d_in, const int* in_sizes, int n_in,
                              void* d_out, int out_size, void* d_ws, size_t ws_size,
                              hipStream_t stream) {
    const float* outputs = (const float*)d_in[0];
    const float* targets = (const float*)d_in[1];
    const float* W_dec   = (const float*)d_in[2];
    const float* b_dec   = (const float*)d_in[3];
    float* out = (float*)d_out;
    float* ws  = (float*)d_ws;   // needs 4096 floats = 16 KB

    p2cp_block_kernel<<<NBS, 256, 0, stream>>>(outputs, targets, W_dec, b_dec, ws);
    final_reduce_kernel<<<1, 256, 0, stream>>>(ws, out);
}

// Round 3
// 27.087 us; speedup vs baseline: 1.8215x; 1.5593x over previous
//
#include <hip/hip_runtime.h>
#include <math.h>
#include <float.h>

// Problem constants (fixed by setup_inputs):
//   outputs: [8, 512, 12]            fp32
//   targets: [8, 512, 1, 2, 128]     fp32
//   W_dec:   [12, 256]               fp32
//   b_dec:   [256]                   fp32
//   out:     scalar fp32
#define NCOMP 12
#define NS 128
#define NBS 4096   // 8 * 512

// Storage swizzle for the point array: permute within each 8-point group so
// that own-point setup reads (stride 128B) hit distinct banks. A sum over
// per-point mins is invariant to any bijective relabeling of points, so no
// inverse mapping is ever needed.
__device__ __forceinline__ int swz(int p) { return p ^ ((p >> 3) & 7); }

__global__ __launch_bounds__(256)
void p2cp_block_kernel(const float* __restrict__ outputs,
                       const float* __restrict__ targets,
                       const float* __restrict__ W_dec,
                       const float* __restrict__ b_dec,
                       float* __restrict__ partial) {
    const int bsq = blockIdx.x;      // flattened (b, s)
    const int t   = threadIdx.x;     // 0..255

    __shared__ float4 pts[2 * NS];   // slots 0..127: u side, 128..255: v side, {x,y,|p|^2,0}
    __shared__ float  tmp[2 * NS];   // decoded shapes staging
    __shared__ float  o[NCOMP];
    __shared__ float  red[4];

    if (t < NCOMP) o[t] = outputs[bsq * NCOMP + t];

    // targets per (b,s): [2][128]; coalesced read
    const float* tb = targets + (size_t)bsq * (2 * NS);
    const float tval = tb[t];
    __syncthreads();   // o[] ready

    // Decode: shapes[t] = b_dec[t] + sum_k o[k] * W_dec[k*256 + t]
    float acc = b_dec[t];
    #pragma unroll
    for (int k = 0; k < NCOMP; ++k)
        acc = fmaf(o[k], W_dec[k * 256 + t], acc);
    tmp[t] = acc;

    // v points: thread t<128 owns v-point t: x = tb[t] (=tval), y = tb[128+t]
    if (t < NS) {
        const float vy = tb[NS + t];
        pts[swz(NS + t)] = make_float4(tval, vy, fmaf(tval, tval, vy * vy), 0.0f);
    }
    __syncthreads();   // tmp[] ready

    // u points from decoded shapes: point i: x = tmp[i], y = tmp[128+i]
    if (t >= NS) {
        const int i = t - NS;
        const float x = tmp[i], y = tmp[NS + i];
        pts[swz(i)] = make_float4(x, y, fmaf(x, x, y * y), 0.0f);
    }
    __syncthreads();   // pts[] ready

    // Tiling: group = t>>3 owns 8 stored slots [group*8 .. group*8+7].
    // Groups 0..15 -> u side (min over v slots), groups 16..31 -> v side.
    // slice = t&7 handles candidates j = slice + 8*i, i = 0..15.
    const int slice   = t & 7;
    const int group   = t >> 3;
    const int ownBase = group * 8;                 // 0..248 (storage slots)
    const float4* __restrict__ opp = (ownBase < NS) ? (pts + NS) : pts;

    float a[8], b[8], zz[8], mn[8];
    #pragma unroll
    for (int k = 0; k < 8; ++k) {
        const float4 p = pts[ownBase + k];         // conflict-free thanks to swz
        a[k] = -2.0f * p.x;
        b[k] = -2.0f * p.y;
        zz[k] = p.z;
        mn[k] = FLT_MAX;
    }

    // Gram form: d2(p,q) = |p|^2 + (|q|^2 - 2 px qx - 2 py qy); |p|^2 added at the end.
    #pragma unroll 4
    for (int i = 0; i < 16; i += 2) {
        const float4 q0 = opp[slice + 8 * i];
        const float4 q1 = opp[slice + 8 * i + 8];
        #pragma unroll
        for (int k = 0; k < 8; ++k) {
            const float d0 = fmaf(a[k], q0.x, fmaf(b[k], q0.y, q0.z));
            const float d1 = fmaf(a[k], q1.x, fmaf(b[k], q1.y, q1.z));
            mn[k] = fminf(mn[k], fminf(d0, d1));   // v_min3 candidate
        }
    }

    // Combine partial mins across the 8 slices (adjacent lanes, same wave).
    #pragma unroll
    for (int k = 0; k < 8; ++k) {
        mn[k] = fminf(mn[k], __shfl_xor(mn[k], 1));
        mn[k] = fminf(mn[k], __shfl_xor(mn[k], 2));
        mn[k] = fminf(mn[k], __shfl_xor(mn[k], 4));
    }

    // Lane (group, slice) finalizes stored slot ownBase + slice.
    float mm = mn[0], z = zz[0];
    #pragma unroll
    for (int k = 1; k < 8; ++k) {
        mm = (slice == k) ? mn[k] : mm;
        z  = (slice == k) ? zz[k] : z;
    }
    const float d2 = fmaxf(mm + z, 0.0f);          // matches jnp.maximum(d2, 0)
    float m = sqrtf(d2 + 1e-12f);                  // sqrt monotone: one sqrt after min

    // Block sum of m across 256 threads (wave64 shuffle + LDS).
    #pragma unroll
    for (int off = 32; off > 0; off >>= 1)
        m += __shfl_down(m, off);
    const int lane = t & 63;
    const int wid  = t >> 6;
    if (lane == 0) red[wid] = m;
    __syncthreads();
    if (t == 0) {
        // per-(b,s): 0.5*(u2v.mean + v2u.mean) = blocksum / 256
        partial[bsq] = red[0] + red[1] + red[2] + red[3];
    }
}

__global__ __launch_bounds__(256)
void final_reduce_kernel(const float* __restrict__ partial,
                         float* __restrict__ out) {
    const int t = threadIdx.x;
    float s = 0.0f;
    for (int i = t; i < NBS; i += 256) s += partial[i];
    #pragma unroll
    for (int off = 32; off > 0; off >>= 1)
        s += __shfl_down(s, off);
    __shared__ float red[4];
    const int lane = t & 63;
    const int wid  = t >> 6;
    if (lane == 0) red[wid] = s;
    __syncthreads();
    if (t == 0) {
        float total = red[0] + red[1] + red[2] + red[3];
        out[0] = total * (1.0f / (256.0f * (float)NBS));
    }
}

extern "C" void kernel_launch(void* const* d_in, const int* in_sizes, int n_in,
                              void* d_out, int out_size, void* d_ws, size_t ws_size,
                              hipStream_t stream) {
    const float* outputs = (const float*)d_in[0];
    const float* targets = (const float*)d_in[1];
    const float* W_dec   = (const float*)d_in[2];
    const float* b_dec   = (const float*)d_in[3];
    float* out = (float*)d_out;
    float* ws  = (float*)d_ws;   // needs 4096 floats = 16 KB

    p2cp_block_kernel<<<NBS, 256, 0, stream>>>(outputs, targets, W_dec, b_dec, ws);
    final_reduce_kernel<<<1, 256, 0, stream>>>(ws, out);
}

// Round 5
// 21.408 us; speedup vs baseline: 2.3046x; 1.2652x over previous
//
#include <hip/hip_runtime.h>
#include <math.h>
#include <float.h>

// Problem constants (fixed by setup_inputs):
//   outputs: [8, 512, 12]            fp32
//   targets: [8, 512, 1, 2, 128]     fp32
//   W_dec:   [12, 256]               fp32
//   b_dec:   [256]                   fp32
//   out:     scalar fp32
#define NCOMP 12
#define NS 128
#define NBS 4096   // 8 * 512

// Data-placement swizzle for pack WRITES. Reads are slot-indexed; a sum over
// per-point mins is invariant to bijective relabeling, so no inverse needed.
__device__ __forceinline__ int swz(int p) { return p ^ ((p >> 3) & 7); }

__global__ __launch_bounds__(256)
void p2cp_block_kernel(const float* __restrict__ outputs,
                       const float* __restrict__ targets,
                       const float* __restrict__ W_dec,
                       const float* __restrict__ b_dec,
                       float* __restrict__ partial) {
    const int bsq = blockIdx.x;      // flattened (b, s)
    const int t   = threadIdx.x;     // 0..255

    __shared__ __align__(16) float2 sxy[2 * NS];  // slots 0..127 u, 128..255 v: {x,y}
    __shared__ __align__(16) float  szz[2 * NS];  // |p|^2 per slot
    __shared__ float o[NCOMP];
    __shared__ float red[4];

    if (t < NCOMP) o[t] = outputs[bsq * NCOMP + t];

    // targets per (b,s): [2][128]
    const float* tb = targets + (size_t)bsq * (2 * NS);
    const float tval = tb[t];
    float vx2 = 0.0f;
    if (t >= NS) vx2 = tb[t - NS];   // x-coord for v-point t-128
    __syncthreads();   // o[] ready

    if (t < NS) {
        // decode BOTH coords of u-point t: x = shapes[t], y = shapes[128+t]
        float x = b_dec[t], y = b_dec[NS + t];
        #pragma unroll
        for (int k = 0; k < NCOMP; ++k) {
            x = fmaf(o[k], W_dec[k * 256 + t], x);
            y = fmaf(o[k], W_dec[k * 256 + NS + t], y);
        }
        const int s = swz(t);
        sxy[s] = make_float2(x, y);
        szz[s] = fmaf(x, x, y * y);
    } else {
        // v-point j = t-128: x = tb[j], y = tb[128+j] = tval
        const int j = t - NS;
        const float x = vx2, y = tval;
        const int s = swz(NS + j);
        sxy[s] = make_float2(x, y);
        szz[s] = fmaf(x, x, y * y);
    }
    __syncthreads();   // points ready

    // Tiling: group = t>>3 owns 8 stored slots [group*8, group*8+8).
    // Groups 0..15 -> u side (min over v slots), 16..31 -> v side.
    // slice = t&7 handles candidate slot-pairs m = slice + 8i (slots 2m, 2m+1).
    const int slice   = t & 7;
    const int group   = t >> 3;
    const int ownBase = group * 8;
    const float* opp_xy = reinterpret_cast<const float*>((ownBase < NS) ? (sxy + NS) : sxy);
    const float* opp_zz = (ownBase < NS) ? (szz + NS) : szz;

    float a[8], b[8], mn[8];
    #pragma unroll
    for (int k = 0; k < 8; ++k) {
        const float2 p = sxy[ownBase + k];
        a[k] = -2.0f * p.x;
        b[k] = -2.0f * p.y;
        mn[k] = FLT_MAX;
    }

    // Gram form: d2(p,q) = |p|^2 + (|q|^2 - 2 px qx - 2 py qy); |p|^2 added at end.
    #pragma unroll 4
    for (int i = 0; i < 8; ++i) {
        const int m = slice + 8 * i;                 // candidate slot-pair index
        const float4 q  = *reinterpret_cast<const float4*>(opp_xy + 4 * m); // {x0,y0,x1,y1}
        const float2 z2 = *reinterpret_cast<const float2*>(opp_zz + 2 * m); // {z0,z1}
        #pragma unroll
        for (int k = 0; k < 8; ++k) {
            const float d0 = fmaf(a[k], q.x, fmaf(b[k], q.y, z2.x));
            const float d1 = fmaf(a[k], q.z, fmaf(b[k], q.w, z2.y));
            mn[k] = fminf(mn[k], fminf(d0, d1));     // v_min3 candidate
        }
    }

    // Combine partial mins across the 8 slices (adjacent lanes, same wave).
    #pragma unroll
    for (int k = 0; k < 8; ++k) {
        mn[k] = fminf(mn[k], __shfl_xor(mn[k], 1));
        mn[k] = fminf(mn[k], __shfl_xor(mn[k], 2));
        mn[k] = fminf(mn[k], __shfl_xor(mn[k], 4));
    }

    // Lane (group, slice) finalizes stored slot ownBase + slice == t.
    float mm = mn[0];
    #pragma unroll
    for (int k = 1; k < 8; ++k) mm = (slice == k) ? mn[k] : mm;
    const float d2 = fmaxf(mm + szz[t], 0.0f);       // own |p|^2 lives at slot t
    float m = sqrtf(d2 + 1e-12f);                    // sqrt monotone: one sqrt after min

    // Block sum across 256 threads.
    #pragma unroll
    for (int off = 32; off > 0; off >>= 1)
        m += __shfl_down(m, off);
    const int lane = t & 63;
    const int wid  = t >> 6;
    if (lane == 0) red[wid] = m;
    __syncthreads();
    if (t == 0) {
        // per-(b,s): 0.5*(u2v.mean + v2u.mean) = blocksum / 256
        partial[bsq] = red[0] + red[1] + red[2] + red[3];
    }
}

__global__ __launch_bounds__(256)
void final_reduce_kernel(const float* __restrict__ partial,
                         float* __restrict__ out) {
    const int t = threadIdx.x;
    float s = 0.0f;
    #pragma unroll
    for (int i = 0; i < 16; ++i) s += partial[t + 256 * i];
    #pragma unroll
    for (int off = 32; off > 0; off >>= 1)
        s += __shfl_down(s, off);
    __shared__ float red[4];
    const int lane = t & 63;
    const int wid  = t >> 6;
    if (lane == 0) red[wid] = s;
    __syncthreads();
    if (t == 0) {
        float total = red[0] + red[1] + red[2] + red[3];
        out[0] = total * (1.0f / (256.0f * (float)NBS));
    }
}

extern "C" void kernel_launch(void* const* d_in, const int* in_sizes, int n_in,
                              void* d_out, int out_size, void* d_ws, size_t ws_size,
                              hipStream_t stream) {
    const float* outputs = (const float*)d_in[0];
    const float* targets = (const float*)d_in[1];
    const float* W_dec   = (const float*)d_in[2];
    const float* b_dec   = (const float*)d_in[3];
    float* out = (float*)d_out;
    float* ws  = (float*)d_ws;   // 4096 floats = 16 KB (same layout R3 used successfully)

    p2cp_block_kernel<<<NBS, 256, 0, stream>>>(outputs, targets, W_dec, b_dec, ws);
    final_reduce_kernel<<<1, 256, 0, stream>>>(ws, out);
}